// Round 2
// baseline (388.649 us; speedup 1.0000x reference)
//
#include <hip/hip_runtime.h>

#define N_NODES 50000
#define N_EDGES 800000
#define NGRAPH  128
#define XPITCH  72   // ushort pitch: 72*2=144B, 16B-aligned rows, 2-way (free) banks
#define NB      391  // dst buckets of 128 nodes
#define HEPB    4096
#define SEPB    8192
#define ECAP    512  // per-wave cached edge metas (mean 256, +16 sigma; slow fallback beyond)
#define APITCH  66   // f32 agg pitch (bank-spread across rows)
#define UNR     8    // edges in flight per lane in agg loop

typedef short bf16x8 __attribute__((ext_vector_type(8)));
typedef float f32x4  __attribute__((ext_vector_type(4)));

// ---------------------------------------------------------------------------
// helpers
// ---------------------------------------------------------------------------

__device__ __forceinline__ float atomAddF(float* p, float v) {
#if defined(__gfx950__) || defined(__AMDGCN__)
    return unsafeAtomicAdd(p, v);
#else
    return atomicAdd(p, v);
#endif
}

__device__ __forceinline__ unsigned short f2bf(float x) {  // RNE f32 -> bf16
    unsigned u = __builtin_bit_cast(unsigned, x);
    u += 0x7fffu + ((u >> 16) & 1u);
    return (unsigned short)(u >> 16);
}
__device__ __forceinline__ float bf2f(unsigned short h) {
    return __builtin_bit_cast(float, (unsigned)h << 16);
}

__device__ __forceinline__ f32x4 mk4(float b) { f32x4 a = {b, b, b, b}; return a; }

// One 16x16 tile vs weight mat, A-frags preloaded in regs.
template<int NKC, int KROW>
__device__ __forceinline__ f32x4 w_tile(const bf16x8* a,
                                        const unsigned short* __restrict__ Wm,
                                        int nt, int col, int quad, f32x4 acc) {
    const unsigned short* wp = Wm + (nt * 16 + col) * KROW + quad * 8;
#pragma unroll
    for (int c = 0; c < NKC; ++c) {
        bf16x8 b = *(const bf16x8*)(wp + c * 32);
        acc = __builtin_amdgcn_mfma_f32_16x16x32_bf16(a[c], b, acc, 0, 0, 0);
    }
    return acc;
}

// load A-frags (wave-private slice, rows = local m, m=col)
template<int NKC>
__device__ __forceinline__ void a_load(const unsigned short* __restrict__ sl,
                                       int col, int quad, bf16x8* a) {
    a[0] = *(const bf16x8*)(sl + col * XPITCH + quad * 8);
    if (NKC > 1) a[1] = *(const bf16x8*)(sl + col * XPITCH + quad * 8 + 32);
}

// write NNT n-tiles back into wave slice (in place; all A reads already done)
template<int NNT>
__device__ __forceinline__ void w_store(unsigned short* __restrict__ sl,
                                        int col, int quad, const f32x4* acc4,
                                        bool relu) {
#pragma unroll
    for (int nt = 0; nt < NNT; ++nt)
#pragma unroll
        for (int r = 0; r < 4; ++r) {
            float x = acc4[nt][r];
            if (relu) x = fmaxf(x, 0.f);
            sl[(quad * 4 + r) * XPITCH + nt * 16 + col] = f2bf(x);
        }
}

// store 4 n-tiles to global rows (node-major bf16[64])
__device__ __forceinline__ void g_store(unsigned short* __restrict__ g, int gn0,
                                        int col, int quad, const f32x4* acc4) {
#pragma unroll
    for (int nt = 0; nt < 4; ++nt)
#pragma unroll
        for (int r = 0; r < 4; ++r) {
            int node = gn0 + quad * 4 + r;
            if (node < N_NODES)
                g[(size_t)node * 64 + nt * 16 + col] = f2bf(acc4[nt][r]);
        }
}

// edge meta: (local dst m << 16) | src   via 4-step binary search over rp[0..16]
__device__ __forceinline__ unsigned edgeMeta(const unsigned short* __restrict__ srcList,
                                             const int* rp, int b0, int idx) {
    int ge = b0 + idx;
    int lo = 0, hi = 16;
#pragma unroll
    for (int s = 0; s < 4; ++s) {
        int md = (lo + hi) >> 1;
        if (rp[md] <= ge) lo = md; else hi = md;
    }
    return ((unsigned)lo << 16) | (unsigned)srcList[ge];
}

// ---------------------------------------------------------------------------
// edge-parallel per-wave aggregation: agg[m][c] = sum_e relu(u[m][c]+v[src][c])
// over the wave's contiguous edge range [rp[0],rp[16]). 16 lanes/edge (col =
// 4-channel group), quarter q streams consecutive edges i0+q*UNR+j; each round
// batches 8 independent gathers per lane, then accumulates with a run-cache
// (edges dst-sorted -> few LDS-atomic flushes). Result written as bf16 into
// the wave's SL slice rows [m][0..63]. Wave-private: no barriers.
// ---------------------------------------------------------------------------
__device__ __forceinline__ void edge_agg(const int* rp, unsigned short* __restrict__ sl,
                                         float* __restrict__ agg, unsigned* __restrict__ em,
                                         const unsigned short* __restrict__ u,
                                         const unsigned short* __restrict__ vin,
                                         const unsigned short* __restrict__ srcList,
                                         int gn0, int lane) {
    int col = lane & 15, q = lane >> 4;
    int b0 = rp[0];
    int nE = rp[16] - b0;

    // wave's own u rows -> SL (bf16); zeros for invalid nodes
    const uint4* ug = (const uint4*)(u + (size_t)gn0 * 64);
    for (int i = lane; i < 128; i += 64) {
        int m = i >> 3, sg = i & 7;
        uint4 d = (gn0 + m < N_NODES) ? ug[i] : make_uint4(0u, 0u, 0u, 0u);
        *(uint4*)&sl[m * XPITCH + sg * 8] = d;
    }
    // zero agg
    for (int i = lane; i < 16 * APITCH; i += 64) agg[i] = 0.f;
    // edge meta cache (coalesced srcList read + binary search, once per edge)
    int nC = min(nE, ECAP);
    for (int i = lane; i < nC; i += 64) em[i] = edgeMeta(srcList, rp, b0, i);

    int curM = -1;
    float ac0 = 0.f, ac1 = 0.f, ac2 = 0.f, ac3 = 0.f;
    float uu0 = 0.f, uu1 = 0.f, uu2 = 0.f, uu3 = 0.f;
    for (int i0 = 0; i0 < nE; i0 += 4 * UNR) {
        int mm[UNR]; ushort4 vv[UNR];
#pragma unroll
        for (int j = 0; j < UNR; ++j) {
            int idx = i0 + q * UNR + j;
            unsigned meta = 0u;
            if (idx < nE) meta = (idx < ECAP) ? em[idx] : edgeMeta(srcList, rp, b0, idx);
            mm[j] = (idx < nE) ? (int)(meta >> 16) : -1;
            int s = (int)(meta & 0xffffu);
            vv[j] = *(const ushort4*)(vin + (size_t)s * 64 + col * 4);  // row 0 if inactive
        }
#pragma unroll
        for (int j = 0; j < UNR; ++j) {
            if (mm[j] >= 0) {
                if (mm[j] != curM) {
                    if (curM >= 0) {
                        float* ap = agg + curM * APITCH + col * 4;
                        atomicAdd(ap + 0, ac0); atomicAdd(ap + 1, ac1);
                        atomicAdd(ap + 2, ac2); atomicAdd(ap + 3, ac3);
                    }
                    curM = mm[j];
                    ushort4 uu = *(const ushort4*)&sl[curM * XPITCH + col * 4];
                    uu0 = bf2f(uu.x); uu1 = bf2f(uu.y); uu2 = bf2f(uu.z); uu3 = bf2f(uu.w);
                    ac0 = ac1 = ac2 = ac3 = 0.f;
                }
                ac0 += fmaxf(uu0 + bf2f(vv[j].x), 0.f);
                ac1 += fmaxf(uu1 + bf2f(vv[j].y), 0.f);
                ac2 += fmaxf(uu2 + bf2f(vv[j].z), 0.f);
                ac3 += fmaxf(uu3 + bf2f(vv[j].w), 0.f);
            }
        }
    }
    if (curM >= 0) {
        float* ap = agg + curM * APITCH + col * 4;
        atomicAdd(ap + 0, ac0); atomicAdd(ap + 1, ac1);
        atomicAdd(ap + 2, ac2); atomicAdd(ap + 3, ac3);
    }

    // agg (f32) -> SL bf16 rows
    for (int i = lane; i < 512; i += 64) {
        int m = i >> 5, c2 = (i & 31) << 1;
        unsigned pk = (unsigned)f2bf(agg[m * APITCH + c2])
                    | ((unsigned)f2bf(agg[m * APITCH + c2 + 1]) << 16);
        *(unsigned*)&sl[m * XPITCH + c2] = pk;
    }
}

// ---------------------------------------------------------------------------
// weight prep (transpose + bf16 into B-operand layout); also zeroes gHist/out
// ---------------------------------------------------------------------------
#define OFF_NW1T  0
#define OFF_NW2T  2048
#define OFF_LYR   6144
#define LYR_SZ    20480
#define OFF_LIN1T 67584
#define OFF_LIN2T 69632
#define WT_TOTAL  70144

__global__ __launch_bounds__(256) void kPrep(
    const float* __restrict__ nW1, const float* __restrict__ nW2,
    const float* __restrict__ lW1, const float* __restrict__ lW2,
    const float* __restrict__ gW1, const float* __restrict__ gW2,
    const float* __restrict__ lin1W, const float* __restrict__ lin2W,
    unsigned short* __restrict__ WT, int* __restrict__ gHist,
    float* __restrict__ out) {
    int i = blockIdx.x * 256 + threadIdx.x;
    if (blockIdx.x == 0) {
        for (int k = threadIdx.x; k < NB; k += 256) gHist[k] = 0;
        for (int k = threadIdx.x; k < NGRAPH * 8; k += 256) out[k] = 0.f;
    }
    if (i >= WT_TOTAL) return;
    int j = i;
    if (j < 2048) {
        int n = j >> 5, k = j & 31;
        WT[i] = (k < 16) ? f2bf(nW1[k * 64 + n]) : 0;
        return;
    }
    j -= 2048;
    if (j < 4096) {
        int n = j >> 6, k = j & 63;
        WT[i] = f2bf(nW2[k * 64 + n]);
        return;
    }
    j -= 4096;
    if (j < 3 * LYR_SZ) {
        int l = j / LYR_SZ;  j -= l * LYR_SZ;
        int m = j >> 12;     j &= 4095;
        int n = j >> 6, k = j & 63;
        const float* src;
        if (m == 0)      src = lW1 + (size_t)l * 131 * 64;
        else if (m == 1) src = lW1 + (size_t)l * 131 * 64 + 64 * 64;
        else if (m == 2) src = lW2 + (size_t)l * 4096;
        else if (m == 3) src = gW1 + (size_t)l * 4096;
        else             src = gW2 + (size_t)l * 4096;
        WT[i] = f2bf(src[k * 64 + n]);
        return;
    }
    j -= 3 * LYR_SZ;
    if (j < 2048) {
        int n = j >> 6, k = j & 63;
        WT[i] = f2bf(lin1W[k * 32 + n]);
        return;
    }
    j -= 2048;
    {
        int n = j >> 5, k = j & 31;
        WT[i] = (n < 8) ? f2bf(lin2W[k * 8 + n]) : 0;
    }
}

// ---------------------------------------------------------------------------
// bucket build: hist -> scan -> bucket scatter -> per-bucket counting sort
// ---------------------------------------------------------------------------
__global__ __launch_bounds__(256) void kHist(const int* __restrict__ ei,
                                             int* __restrict__ gHist) {
    __shared__ int h[NB];
    int tid = threadIdx.x;
    for (int i = tid; i < NB; i += 256) h[i] = 0;
    __syncthreads();
    int base = blockIdx.x * HEPB;
#pragma unroll
    for (int k = 0; k < HEPB; k += 256) {
        int e = base + k + tid;
        if (e < N_EDGES) atomicAdd(&h[ei[N_EDGES + e] >> 7], 1);
    }
    __syncthreads();
    for (int i = tid; i < NB; i += 256)
        if (h[i]) atomicAdd(&gHist[i], h[i]);
}

__global__ __launch_bounds__(256) void kScanB(const int* __restrict__ gHist,
                                              int* __restrict__ bucketOff,
                                              int* __restrict__ cursor) {
    __shared__ int s0[512], s1[512];
    int tid = threadIdx.x;
    for (int e = tid; e < 512; e += 256) s0[e] = (e < NB) ? gHist[e] : 0;
    __syncthreads();
    int* sp = s0; int* dp = s1;
    for (int off = 1; off < 512; off <<= 1) {
        for (int e = tid; e < 512; e += 256)
            dp[e] = sp[e] + ((e >= off) ? sp[e - off] : 0);
        __syncthreads();
        int* t = sp; sp = dp; dp = t;
    }
    for (int e = tid; e < NB; e += 256) {
        int excl = sp[e] - gHist[e];
        bucketOff[e] = excl;
        cursor[e] = excl;
    }
    if (tid == 0) bucketOff[NB] = sp[NB - 1];
}

__global__ __launch_bounds__(256) void kScat(const int* __restrict__ ei,
                                             int* __restrict__ cursor,
                                             int* __restrict__ packs) {
    __shared__ int sdata[SEPB];
    __shared__ int hist[NB];
    __shared__ int loff[NB + 1];
    __shared__ int gbase[NB];
    __shared__ int sc0[512], sc1[512];
    int tid = threadIdx.x;
    int base = blockIdx.x * SEPB;
    int nE = min(SEPB, N_EDGES - base);

    for (int i = tid; i < NB; i += 256) hist[i] = 0;
    __syncthreads();

    int myPack[SEPB / 256];
    unsigned short myRank[SEPB / 256];
#pragma unroll
    for (int kk = 0; kk < SEPB / 256; ++kk) {
        int e = base + kk * 256 + tid;
        if (e < N_EDGES) {
            int s = ei[e], d = ei[N_EDGES + e];
            myPack[kk] = (s << 16) | d;
            myRank[kk] = (unsigned short)atomicAdd(&hist[d >> 7], 1);
        }
    }
    __syncthreads();

    for (int e = tid; e < 512; e += 256) sc0[e] = (e < NB) ? hist[e] : 0;
    __syncthreads();
    int* sp = sc0; int* dp = sc1;
    for (int off = 1; off < 512; off <<= 1) {
        for (int e = tid; e < 512; e += 256)
            dp[e] = sp[e] + ((e >= off) ? sp[e - off] : 0);
        __syncthreads();
        int* t = sp; sp = dp; dp = t;
    }
    for (int e = tid; e < NB; e += 256) loff[e] = sp[e] - hist[e];
    if (tid == 0) loff[NB] = sp[NB - 1];
    __syncthreads();

    for (int e = tid; e < NB; e += 256)
        gbase[e] = hist[e] ? atomicAdd(&cursor[e], hist[e]) : 0;
#pragma unroll
    for (int kk = 0; kk < SEPB / 256; ++kk) {
        int e = base + kk * 256 + tid;
        if (e < N_EDGES) {
            int p = myPack[kk];
            int b = (p & 0xffff) >> 7;
            sdata[loff[b] + myRank[kk]] = p;
        }
    }
    __syncthreads();

    for (int i = tid; i < nE; i += 256) {
        int p = sdata[i];
        int b = (p & 0xffff) >> 7;
        packs[gbase[b] + (i - loff[b])] = p;
    }
}

// ---------------------------------------------------------------------------
// kSortA: merged dispatch. Blocks [0,NB): per-bucket counting sort.
// Blocks [NB, NB+nodeBlocks): kA node pipelines. Independent halves overlap.
// ---------------------------------------------------------------------------
__global__ __launch_bounds__(256) void kSortA(
    const int* __restrict__ bucketOff, const int* __restrict__ packs,
    unsigned short* __restrict__ srcList, int* __restrict__ rowPtr,
    const float* __restrict__ x, const float* __restrict__ pos,
    const unsigned short* __restrict__ WT,
    const float* __restrict__ nb1, const float* __restrict__ nb2,
    const float* __restrict__ lW1f, const float* __restrict__ lb1,
    unsigned short* __restrict__ u, unsigned short* __restrict__ v) {
    __shared__ int hist[128];
    __shared__ int cur[128];
    __shared__ int sc0[128], sc1[128];
    __shared__ unsigned short SL[4 * 16 * XPITCH];
    __shared__ float posW[4 * 48];

    int tid = threadIdx.x;
    if (blockIdx.x < NB) {
        // ---- kSort body ----
        int nbk = blockIdx.x;
        int nodeBase = nbk * 128;
        int nvalid = min(128, N_NODES - nodeBase);
        int eb = bucketOff[nbk], ee = bucketOff[nbk + 1];

        if (tid < 128) hist[tid] = 0;
        __syncthreads();
        for (int i = eb + tid; i < ee; i += 256)
            atomicAdd(&hist[packs[i] & 127], 1);
        __syncthreads();

        if (tid < 128) sc0[tid] = hist[tid];
        __syncthreads();
        int* sp = sc0; int* dp = sc1;
        for (int off = 1; off < 128; off <<= 1) {
            if (tid < 128) dp[tid] = sp[tid] + ((tid >= off) ? sp[tid - off] : 0);
            __syncthreads();
            int* t = sp; sp = dp; dp = t;
        }
        if (tid < 128) {
            int excl = eb + sp[tid] - hist[tid];
            if (tid < nvalid) rowPtr[nodeBase + tid] = excl;
            cur[tid] = excl;
        }
        if (nbk == NB - 1 && tid == 0) rowPtr[N_NODES] = ee;
        __syncthreads();

        for (int i = eb + tid; i < ee; i += 256) {
            int p = packs[i];
            int ps = atomicAdd(&cur[p & 127], 1);
            srcList[ps] = (unsigned short)(((unsigned)p) >> 16);
        }
        return;
    }

    // ---- kA body (barrier-free wave pipelines, 16 nodes/wave) ----
    int bid = blockIdx.x - NB;
    int lane = tid & 63;
    int wv = __builtin_amdgcn_readfirstlane(tid >> 6);
    unsigned short* sl = SL + wv * 16 * XPITCH;
    float* pw = posW + wv * 48;
    int gn0 = bid * 64 + wv * 16;
    int col = lane & 15, quad = lane >> 4;

    for (int idx = lane; idx < 512; idx += 64) {
        int m = idx >> 5, k = idx & 31;
        int node = gn0 + m;
        float val = (k < 16 && node < N_NODES) ? x[(size_t)node * 16 + k] : 0.f;
        sl[m * XPITCH + k] = f2bf(val);
    }
    for (int idx = lane; idx < 48; idx += 64) {
        int node = gn0 + idx / 3;
        pw[idx] = (node < N_NODES) ? pos[(size_t)node * 3 + idx % 3] : 0.f;
    }

    bf16x8 a[2];
    f32x4 acc4[4];

    a_load<1>(sl, col, quad, a);
#pragma unroll
    for (int nt = 0; nt < 4; ++nt)
        acc4[nt] = w_tile<1, 32>(a, WT + OFF_NW1T, nt, col, quad, mk4(nb1[nt * 16 + col]));
    w_store<4>(sl, col, quad, acc4, true);

    a_load<2>(sl, col, quad, a);
#pragma unroll
    for (int nt = 0; nt < 4; ++nt)
        acc4[nt] = w_tile<2, 64>(a, WT + OFF_NW2T, nt, col, quad, mk4(nb2[nt * 16 + col]));
    w_store<4>(sl, col, quad, acc4, false);

    const unsigned short* aT = WT + OFF_LYR;
    const unsigned short* bT = aT + 4096;
    const float* W1c = lW1f + 128 * 64;

    a_load<2>(sl, col, quad, a);
#pragma unroll
    for (int nt = 0; nt < 4; ++nt)
        acc4[nt] = w_tile<2, 64>(a, aT, nt, col, quad, mk4(0.f));
    g_store(u, gn0, col, quad, acc4);

    float px[4], py[4], pz[4];
#pragma unroll
    for (int r = 0; r < 4; ++r) {
        px[r] = pw[(quad * 4 + r) * 3 + 0];
        py[r] = pw[(quad * 4 + r) * 3 + 1];
        pz[r] = pw[(quad * 4 + r) * 3 + 2];
    }
#pragma unroll
    for (int nt = 0; nt < 4; ++nt) {
        int ch = nt * 16 + col;
        acc4[nt] = w_tile<2, 64>(a, bT, nt, col, quad, mk4(lb1[ch]));
        float w0 = W1c[ch], w1 = W1c[64 + ch], w2 = W1c[128 + ch];
#pragma unroll
        for (int r = 0; r < 4; ++r)
            acc4[nt][r] += px[r] * w0 + py[r] * w1 + pz[r] * w2;
    }
    g_store(v, gn0, col, quad, acc4);
}

// ---------------------------------------------------------------------------
// kB (layers 0,1): edge-parallel fused aggregation + node pipelines.
// u updated in place (own rows only, read first); v ping-pong (vin/vout).
// ---------------------------------------------------------------------------
__global__ __launch_bounds__(256) void kB(
    const float* __restrict__ pos,
    const int* __restrict__ rowPtr, const unsigned short* __restrict__ srcList,
    const unsigned short* __restrict__ WT, int l,
    const float* __restrict__ lb2, const float* __restrict__ gb1,
    const float* __restrict__ gb2,
    const float* __restrict__ lW1f_next, const float* __restrict__ b1n,
    unsigned short* __restrict__ u,
    const unsigned short* __restrict__ vin,
    unsigned short* __restrict__ vout) {
    __shared__ unsigned short SL[4 * 16 * XPITCH];
    __shared__ float posW[4 * 48];
    __shared__ int rpW[4][17];
    __shared__ float aggW[4][16 * APITCH];
    __shared__ unsigned emW[4][ECAP];
    int tid = threadIdx.x;
    int lane = tid & 63;
    int wv = __builtin_amdgcn_readfirstlane(tid >> 6);
    unsigned short* sl = SL + wv * 16 * XPITCH;
    float* pw = posW + wv * 48;
    int* rp = rpW[wv];
    int gn0 = blockIdx.x * 64 + wv * 16;
    int col = lane & 15, quad = lane >> 4;

    const unsigned short* LYR = WT + OFF_LYR + (size_t)l * LYR_SZ;
    const unsigned short* lW2T = LYR + 2 * 4096;
    const unsigned short* gW1T = LYR + 3 * 4096;
    const unsigned short* gW2T = LYR + 4 * 4096;
    const unsigned short* aTn = WT + OFF_LYR + (size_t)(l + 1) * LYR_SZ;
    const unsigned short* bTn = aTn + 4096;

    if (lane < 17) rp[lane] = rowPtr[min(gn0 + lane, N_NODES)];
    for (int idx = lane; idx < 48; idx += 64) {
        int node = gn0 + idx / 3;
        pw[idx] = (node < N_NODES) ? pos[(size_t)node * 3 + idx % 3] : 0.f;
    }

    edge_agg(rp, sl, aggW[wv], emW[wv], u, vin, srcList, gn0, lane);

    bf16x8 a[2];
    f32x4 acc4[4];
    float dgr[4];
#pragma unroll
    for (int r = 0; r < 4; ++r)
        dgr[r] = (float)(rp[quad * 4 + r + 1] - rp[quad * 4 + r]);

    a_load<2>(sl, col, quad, a);
#pragma unroll
    for (int nt = 0; nt < 4; ++nt) {
        float b = lb2[nt * 16 + col];
        f32x4 init = {dgr[0] * b, dgr[1] * b, dgr[2] * b, dgr[3] * b};
        acc4[nt] = w_tile<2, 64>(a, lW2T, nt, col, quad, init);
    }
    w_store<4>(sl, col, quad, acc4, false);

    a_load<2>(sl, col, quad, a);
#pragma unroll
    for (int nt = 0; nt < 4; ++nt)
        acc4[nt] = w_tile<2, 64>(a, gW1T, nt, col, quad, mk4(gb1[nt * 16 + col]));
    w_store<4>(sl, col, quad, acc4, true);

    a_load<2>(sl, col, quad, a);
#pragma unroll
    for (int nt = 0; nt < 4; ++nt)
        acc4[nt] = w_tile<2, 64>(a, gW2T, nt, col, quad, mk4(gb2[nt * 16 + col]));
    w_store<4>(sl, col, quad, acc4, true);

    a_load<2>(sl, col, quad, a);
#pragma unroll
    for (int nt = 0; nt < 4; ++nt)
        acc4[nt] = w_tile<2, 64>(a, aTn, nt, col, quad, mk4(0.f));
    g_store(u, gn0, col, quad, acc4);

    const float* W1c = lW1f_next + 128 * 64;
    float px[4], py[4], pz[4];
#pragma unroll
    for (int r = 0; r < 4; ++r) {
        px[r] = pw[(quad * 4 + r) * 3 + 0];
        py[r] = pw[(quad * 4 + r) * 3 + 1];
        pz[r] = pw[(quad * 4 + r) * 3 + 2];
    }
#pragma unroll
    for (int nt = 0; nt < 4; ++nt) {
        int ch = nt * 16 + col;
        acc4[nt] = w_tile<2, 64>(a, bTn, nt, col, quad, mk4(b1n[ch]));
        float w0 = W1c[ch], w1 = W1c[64 + ch], w2 = W1c[128 + ch];
#pragma unroll
        for (int r = 0; r < 4; ++r)
            acc4[nt][r] += px[r] * w0 + py[r] * w1 + pz[r] * w2;
    }
    g_store(vout, gn0, col, quad, acc4);
}

// ---------------------------------------------------------------------------
// kC (layer 2): edge-parallel fused aggregation + pipelines + readout bins
// ---------------------------------------------------------------------------
__global__ __launch_bounds__(256) void kC(
    const int* __restrict__ rowPtr, const unsigned short* __restrict__ srcList,
    const int* __restrict__ batch, const unsigned short* __restrict__ WT,
    const float* __restrict__ lb2, const float* __restrict__ gb1,
    const float* __restrict__ gb2,
    const float* __restrict__ lin1b, const float* __restrict__ lin2b,
    const unsigned short* __restrict__ u, const unsigned short* __restrict__ vin,
    float* __restrict__ out) {
    __shared__ unsigned short SL[4 * 16 * XPITCH];
    __shared__ int rpW[4][17];
    __shared__ int batchW[64];
    __shared__ float bins[128 * 8];
    __shared__ float aggW[4][16 * APITCH];
    __shared__ unsigned emW[4][ECAP];
    int tid = threadIdx.x;
    int lane = tid & 63;
    int wv = __builtin_amdgcn_readfirstlane(tid >> 6);
    unsigned short* sl = SL + wv * 16 * XPITCH;
    int* rp = rpW[wv];
    int nodeBase = blockIdx.x * 64;
    int gn0 = nodeBase + wv * 16;
    int nvalid = min(64, N_NODES - nodeBase);
    int col = lane & 15, quad = lane >> 4;

    const unsigned short* LYR = WT + OFF_LYR + 2 * LYR_SZ;
    const unsigned short* lW2T = LYR + 2 * 4096;
    const unsigned short* gW1T = LYR + 3 * 4096;
    const unsigned short* gW2T = LYR + 4 * 4096;
    const unsigned short* lin1T = WT + OFF_LIN1T;
    const unsigned short* lin2T = WT + OFF_LIN2T;

    for (int idx = tid; idx < 128 * 8; idx += 256) bins[idx] = 0.f;
    if (lane < 17) rp[lane] = rowPtr[min(gn0 + lane, N_NODES)];
    if (lane < 16) {
        int node = min(gn0 + lane, N_NODES - 1);
        batchW[wv * 16 + lane] = batch[node];
    }
    __syncthreads();   // bins zero + batchW visible before any atomic add

    edge_agg(rp, sl, aggW[wv], emW[wv], u, vin, srcList, gn0, lane);

    bf16x8 a[2];
    f32x4 acc4[4];
    float dgr[4];
#pragma unroll
    for (int r = 0; r < 4; ++r)
        dgr[r] = (float)(rp[quad * 4 + r + 1] - rp[quad * 4 + r]);

    a_load<2>(sl, col, quad, a);
#pragma unroll
    for (int nt = 0; nt < 4; ++nt) {
        float b = lb2[nt * 16 + col];
        f32x4 init = {dgr[0] * b, dgr[1] * b, dgr[2] * b, dgr[3] * b};
        acc4[nt] = w_tile<2, 64>(a, lW2T, nt, col, quad, init);
    }
    w_store<4>(sl, col, quad, acc4, false);

    a_load<2>(sl, col, quad, a);
#pragma unroll
    for (int nt = 0; nt < 4; ++nt)
        acc4[nt] = w_tile<2, 64>(a, gW1T, nt, col, quad, mk4(gb1[nt * 16 + col]));
    w_store<4>(sl, col, quad, acc4, true);

    a_load<2>(sl, col, quad, a);
#pragma unroll
    for (int nt = 0; nt < 4; ++nt)
        acc4[nt] = w_tile<2, 64>(a, gW2T, nt, col, quad, mk4(gb2[nt * 16 + col]));
    w_store<4>(sl, col, quad, acc4, true);

    a_load<2>(sl, col, quad, a);
#pragma unroll
    for (int nt = 0; nt < 2; ++nt)
        acc4[nt] = w_tile<2, 64>(a, lin1T, nt, col, quad, mk4(lin1b[nt * 16 + col]));
    w_store<2>(sl, col, quad, acc4, true);

    a_load<1>(sl, col, quad, a);
    f32x4 o = w_tile<1, 32>(a, lin2T, 0, col, quad,
                            mk4(col < 8 ? lin2b[col] : 0.f));

    int gmin = batch[nodeBase];
    if (col < 8) {
#pragma unroll
        for (int r = 0; r < 4; ++r) {
            int nl = wv * 16 + quad * 4 + r;
            if (nl < nvalid)
                atomicAdd(&bins[(batchW[nl] - gmin) * 8 + col], o[r]);
        }
    }
    __syncthreads();
    int gmax = batch[nodeBase + nvalid - 1];
    int nb8 = (gmax - gmin + 1) * 8;
    for (int idx = tid; idx < nb8; idx += 256)
        atomAddF(&out[gmin * 8 + idx], bins[idx]);
}

// ---------------------------------------------------------------------------
// launch
// ---------------------------------------------------------------------------
extern "C" void kernel_launch(void* const* d_in, const int* in_sizes, int n_in,
                              void* d_out, int out_size, void* d_ws, size_t ws_size,
                              hipStream_t stream) {
    const float* x     = (const float*)d_in[0];
    const float* pos   = (const float*)d_in[1];
    const int*   ei    = (const int*)d_in[2];
    const int*   batch = (const int*)d_in[3];
    const float* nW1   = (const float*)d_in[4];
    const float* nb1   = (const float*)d_in[5];
    const float* nW2   = (const float*)d_in[6];
    const float* nb2   = (const float*)d_in[7];
    const float* lW1   = (const float*)d_in[8];
    const float* lb1   = (const float*)d_in[9];
    const float* lW2   = (const float*)d_in[10];
    const float* lb2   = (const float*)d_in[11];
    const float* gW1   = (const float*)d_in[12];
    const float* gb1   = (const float*)d_in[13];
    const float* gW2   = (const float*)d_in[14];
    const float* gb2   = (const float*)d_in[15];
    const float* lin1W = (const float*)d_in[16];
    const float* lin1b = (const float*)d_in[17];
    const float* lin2W = (const float*)d_in[18];
    const float* lin2b = (const float*)d_in[19];
    float* out = (float*)d_out;

    // workspace: u in-place across layers; v ping-pong (v0/v1)
    unsigned short* u  = (unsigned short*)d_ws;          // N*64 bf16
    unsigned short* v0 = u + (size_t)N_NODES * 64;       // N*64 bf16
    unsigned short* v1 = v0 + (size_t)N_NODES * 64;      // N*64 bf16
    unsigned short* WT = v1 + (size_t)N_NODES * 64;      // WT_TOTAL bf16
    int* gHist = (int*)(WT + WT_TOTAL);                  // NB
    int* bucketOff = gHist + NB;                         // NB+1
    int* cursor = bucketOff + NB + 1;                    // NB
    int* rowPtr = cursor + NB;                           // N+1
    int* packs = rowPtr + N_NODES + 1;                   // E int
    unsigned short* srcList = (unsigned short*)(packs + N_EDGES); // E ushort

    const int nodeBlocks = (N_NODES + 63) / 64;

    kPrep<<<(WT_TOTAL + 255) / 256, 256, 0, stream>>>(nW1, nW2, lW1, lW2, gW1, gW2,
                                                      lin1W, lin2W, WT, gHist, out);
    kHist<<<(N_EDGES + HEPB - 1) / HEPB, 256, 0, stream>>>(ei, gHist);
    kScanB<<<1, 256, 0, stream>>>(gHist, bucketOff, cursor);
    kScat<<<(N_EDGES + SEPB - 1) / SEPB, 256, 0, stream>>>(ei, cursor, packs);
    kSortA<<<NB + nodeBlocks, 256, 0, stream>>>(bucketOff, packs, srcList, rowPtr,
                                                x, pos, WT, nb1, nb2, lW1, lb1,
                                                u, v0);

    kB<<<nodeBlocks, 256, 0, stream>>>(
        pos, rowPtr, srcList, WT, 0,
        lb2 + 0, gb1 + 0, gb2 + 0,
        lW1 + (size_t)1 * 131 * 64, lb1 + 64,
        u, v0, v1);
    kB<<<nodeBlocks, 256, 0, stream>>>(
        pos, rowPtr, srcList, WT, 1,
        lb2 + 64, gb1 + 64, gb2 + 64,
        lW1 + (size_t)2 * 131 * 64, lb1 + 128,
        u, v1, v0);
    kC<<<nodeBlocks, 256, 0, stream>>>(
        rowPtr, srcList, batch, WT,
        lb2 + 128, gb1 + 128, gb2 + 128, lin1b, lin2b,
        u, v0, out);
}

// Round 3
// 292.436 us; speedup vs baseline: 1.3290x; 1.3290x over previous
//
#include <hip/hip_runtime.h>

#define N_NODES 50000
#define N_EDGES 800000
#define NGRAPH  128
#define XPITCH  72   // ushort pitch: 72*2=144B, 16B-aligned rows, 2-way (free) banks
#define NB      391  // dst buckets of 128 nodes
#define HEPB    4096
#define SEPB    8192
#define NGRP    3125 // 16-node groups (50000/16 exact)

typedef short bf16x8 __attribute__((ext_vector_type(8)));
typedef float f32x4  __attribute__((ext_vector_type(4)));

// ---------------------------------------------------------------------------
// helpers
// ---------------------------------------------------------------------------

__device__ __forceinline__ float atomAddF(float* p, float v) {
#if defined(__gfx950__) || defined(__AMDGCN__)
    return unsafeAtomicAdd(p, v);
#else
    return atomicAdd(p, v);
#endif
}

__device__ __forceinline__ unsigned short f2bf(float x) {  // RNE f32 -> bf16
    unsigned u = __builtin_bit_cast(unsigned, x);
    u += 0x7fffu + ((u >> 16) & 1u);
    return (unsigned short)(u >> 16);
}
__device__ __forceinline__ float bf2f(unsigned short h) {
    return __builtin_bit_cast(float, (unsigned)h << 16);
}

__device__ __forceinline__ f32x4 mk4(float b) { f32x4 a = {b, b, b, b}; return a; }

// One 16x16 tile vs weight mat, A-frags preloaded in regs.
template<int NKC, int KROW>
__device__ __forceinline__ f32x4 w_tile(const bf16x8* a,
                                        const unsigned short* __restrict__ Wm,
                                        int nt, int col, int quad, f32x4 acc) {
    const unsigned short* wp = Wm + (nt * 16 + col) * KROW + quad * 8;
#pragma unroll
    for (int c = 0; c < NKC; ++c) {
        bf16x8 b = *(const bf16x8*)(wp + c * 32);
        acc = __builtin_amdgcn_mfma_f32_16x16x32_bf16(a[c], b, acc, 0, 0, 0);
    }
    return acc;
}

// load A-frags from the block-shared 16-node slice (same addrs all waves ->
// LDS broadcast)
template<int NKC>
__device__ __forceinline__ void a_load(const unsigned short* __restrict__ sl,
                                       int col, int quad, bf16x8* a) {
    a[0] = *(const bf16x8*)(sl + col * XPITCH + quad * 8);
    if (NKC > 1) a[1] = *(const bf16x8*)(sl + col * XPITCH + quad * 8 + 32);
}

// write this wave's 16-col tile back into the shared slice
__device__ __forceinline__ void w_store1(unsigned short* __restrict__ sl,
                                         int wv, int col, int quad, f32x4 acc,
                                         bool relu) {
#pragma unroll
    for (int r = 0; r < 4; ++r) {
        float x = acc[r];
        if (relu) x = fmaxf(x, 0.f);
        sl[(quad * 4 + r) * XPITCH + wv * 16 + col] = f2bf(x);
    }
}

// store this wave's 16-col tile to global rows (node-major bf16[64])
__device__ __forceinline__ void g_store1(unsigned short* __restrict__ g, int gn0,
                                         int wv, int col, int quad, f32x4 acc) {
#pragma unroll
    for (int r = 0; r < 4; ++r) {
        int node = gn0 + quad * 4 + r;
        if (node < N_NODES)
            g[(size_t)node * 64 + wv * 16 + col] = f2bf(acc[r]);
    }
}

// ---------------------------------------------------------------------------
// weight prep (transpose + bf16 into B-operand layout); also zeroes gHist/out
// ---------------------------------------------------------------------------
#define OFF_NW1T  0
#define OFF_NW2T  2048
#define OFF_LYR   6144
#define LYR_SZ    20480
#define OFF_LIN1T 67584
#define OFF_LIN2T 69632
#define WT_TOTAL  70144

__global__ __launch_bounds__(256) void kPrep(
    const float* __restrict__ nW1, const float* __restrict__ nW2,
    const float* __restrict__ lW1, const float* __restrict__ lW2,
    const float* __restrict__ gW1, const float* __restrict__ gW2,
    const float* __restrict__ lin1W, const float* __restrict__ lin2W,
    unsigned short* __restrict__ WT, int* __restrict__ gHist,
    float* __restrict__ out) {
    int i = blockIdx.x * 256 + threadIdx.x;
    if (blockIdx.x == 0) {
        for (int k = threadIdx.x; k < NB; k += 256) gHist[k] = 0;
        for (int k = threadIdx.x; k < NGRAPH * 8; k += 256) out[k] = 0.f;
    }
    if (i >= WT_TOTAL) return;
    int j = i;
    if (j < 2048) {
        int n = j >> 5, k = j & 31;
        WT[i] = (k < 16) ? f2bf(nW1[k * 64 + n]) : 0;
        return;
    }
    j -= 2048;
    if (j < 4096) {
        int n = j >> 6, k = j & 63;
        WT[i] = f2bf(nW2[k * 64 + n]);
        return;
    }
    j -= 4096;
    if (j < 3 * LYR_SZ) {
        int l = j / LYR_SZ;  j -= l * LYR_SZ;
        int m = j >> 12;     j &= 4095;
        int n = j >> 6, k = j & 63;
        const float* src;
        if (m == 0)      src = lW1 + (size_t)l * 131 * 64;
        else if (m == 1) src = lW1 + (size_t)l * 131 * 64 + 64 * 64;
        else if (m == 2) src = lW2 + (size_t)l * 4096;
        else if (m == 3) src = gW1 + (size_t)l * 4096;
        else             src = gW2 + (size_t)l * 4096;
        WT[i] = f2bf(src[k * 64 + n]);
        return;
    }
    j -= 3 * LYR_SZ;
    if (j < 2048) {
        int n = j >> 6, k = j & 63;
        WT[i] = f2bf(lin1W[k * 32 + n]);
        return;
    }
    j -= 2048;
    {
        int n = j >> 5, k = j & 31;
        WT[i] = (n < 8) ? f2bf(lin2W[k * 8 + n]) : 0;
    }
}

// ---------------------------------------------------------------------------
// bucket build: hist -> scan -> bucket scatter -> per-bucket counting sort
// ---------------------------------------------------------------------------
__global__ __launch_bounds__(256) void kHist(const int* __restrict__ ei,
                                             int* __restrict__ gHist) {
    __shared__ int h[NB];
    int tid = threadIdx.x;
    for (int i = tid; i < NB; i += 256) h[i] = 0;
    __syncthreads();
    int base = blockIdx.x * HEPB;
#pragma unroll
    for (int k = 0; k < HEPB; k += 256) {
        int e = base + k + tid;
        if (e < N_EDGES) atomicAdd(&h[ei[N_EDGES + e] >> 7], 1);
    }
    __syncthreads();
    for (int i = tid; i < NB; i += 256)
        if (h[i]) atomicAdd(&gHist[i], h[i]);
}

__global__ __launch_bounds__(256) void kScanB(const int* __restrict__ gHist,
                                              int* __restrict__ bucketOff,
                                              int* __restrict__ cursor) {
    __shared__ int s0[512], s1[512];
    int tid = threadIdx.x;
    for (int e = tid; e < 512; e += 256) s0[e] = (e < NB) ? gHist[e] : 0;
    __syncthreads();
    int* sp = s0; int* dp = s1;
    for (int off = 1; off < 512; off <<= 1) {
        for (int e = tid; e < 512; e += 256)
            dp[e] = sp[e] + ((e >= off) ? sp[e - off] : 0);
        __syncthreads();
        int* t = sp; sp = dp; dp = t;
    }
    for (int e = tid; e < NB; e += 256) {
        int excl = sp[e] - gHist[e];
        bucketOff[e] = excl;
        cursor[e] = excl;
    }
    if (tid == 0) bucketOff[NB] = sp[NB - 1];
}

__global__ __launch_bounds__(256) void kScat(const int* __restrict__ ei,
                                             int* __restrict__ cursor,
                                             int* __restrict__ packs) {
    __shared__ int sdata[SEPB];
    __shared__ int hist[NB];
    __shared__ int loff[NB + 1];
    __shared__ int gbase[NB];
    __shared__ int sc0[512], sc1[512];
    int tid = threadIdx.x;
    int base = blockIdx.x * SEPB;
    int nE = min(SEPB, N_EDGES - base);

    for (int i = tid; i < NB; i += 256) hist[i] = 0;
    __syncthreads();

    int myPack[SEPB / 256];
    unsigned short myRank[SEPB / 256];
#pragma unroll
    for (int kk = 0; kk < SEPB / 256; ++kk) {
        int e = base + kk * 256 + tid;
        if (e < N_EDGES) {
            int s = ei[e], d = ei[N_EDGES + e];
            myPack[kk] = (s << 16) | d;
            myRank[kk] = (unsigned short)atomicAdd(&hist[d >> 7], 1);
        }
    }
    __syncthreads();

    for (int e = tid; e < 512; e += 256) sc0[e] = (e < NB) ? hist[e] : 0;
    __syncthreads();
    int* sp = sc0; int* dp = sc1;
    for (int off = 1; off < 512; off <<= 1) {
        for (int e = tid; e < 512; e += 256)
            dp[e] = sp[e] + ((e >= off) ? sp[e - off] : 0);
        __syncthreads();
        int* t = sp; sp = dp; dp = t;
    }
    for (int e = tid; e < NB; e += 256) loff[e] = sp[e] - hist[e];
    if (tid == 0) loff[NB] = sp[NB - 1];
    __syncthreads();

    for (int e = tid; e < NB; e += 256)
        gbase[e] = hist[e] ? atomicAdd(&cursor[e], hist[e]) : 0;
#pragma unroll
    for (int kk = 0; kk < SEPB / 256; ++kk) {
        int e = base + kk * 256 + tid;
        if (e < N_EDGES) {
            int p = myPack[kk];
            int b = (p & 0xffff) >> 7;
            sdata[loff[b] + myRank[kk]] = p;
        }
    }
    __syncthreads();

    for (int i = tid; i < nE; i += 256) {
        int p = sdata[i];
        int b = (p & 0xffff) >> 7;
        packs[gbase[b] + (i - loff[b])] = p;
    }
}

// ---------------------------------------------------------------------------
// kSortA: merged dispatch. Blocks [0,NB): per-bucket counting sort.
// Blocks [NB, NB+NGRP): kA node pipelines (4 waves N-split over one 16-node
// group, barriers between stages). Independent halves overlap.
// ---------------------------------------------------------------------------
__global__ __launch_bounds__(256) void kSortA(
    const int* __restrict__ bucketOff, const int* __restrict__ packs,
    unsigned short* __restrict__ srcList, int* __restrict__ rowPtr,
    const float* __restrict__ x, const float* __restrict__ pos,
    const unsigned short* __restrict__ WT,
    const float* __restrict__ nb1, const float* __restrict__ nb2,
    const float* __restrict__ lW1f, const float* __restrict__ lb1,
    unsigned short* __restrict__ u, unsigned short* __restrict__ v) {
    __shared__ int hist[128];
    __shared__ int cur[128];
    __shared__ int sc0[128], sc1[128];
    __shared__ unsigned short SL[16 * XPITCH];
    __shared__ float pw[48];

    int tid = threadIdx.x;
    if (blockIdx.x < NB) {
        // ---- kSort body ----
        int nbk = blockIdx.x;
        int nodeBase = nbk * 128;
        int nvalid = min(128, N_NODES - nodeBase);
        int eb = bucketOff[nbk], ee = bucketOff[nbk + 1];

        if (tid < 128) hist[tid] = 0;
        __syncthreads();
        for (int i = eb + tid; i < ee; i += 256)
            atomicAdd(&hist[packs[i] & 127], 1);
        __syncthreads();

        if (tid < 128) sc0[tid] = hist[tid];
        __syncthreads();
        int* sp = sc0; int* dp = sc1;
        for (int off = 1; off < 128; off <<= 1) {
            if (tid < 128) dp[tid] = sp[tid] + ((tid >= off) ? sp[tid - off] : 0);
            __syncthreads();
            int* t = sp; sp = dp; dp = t;
        }
        if (tid < 128) {
            int excl = eb + sp[tid] - hist[tid];
            if (tid < nvalid) rowPtr[nodeBase + tid] = excl;
            cur[tid] = excl;
        }
        if (nbk == NB - 1 && tid == 0) rowPtr[N_NODES] = ee;
        __syncthreads();

        for (int i = eb + tid; i < ee; i += 256) {
            int p = packs[i];
            int ps = atomicAdd(&cur[p & 127], 1);
            srcList[ps] = (unsigned short)(((unsigned)p) >> 16);
        }
        return;
    }

    // ---- kA body: one 16-node group, 4 waves N-split ----
    int gn0 = (blockIdx.x - NB) * 16;
    int lane = tid & 63;
    int wv = __builtin_amdgcn_readfirstlane(tid >> 6);
    int col = lane & 15, quad = lane >> 4;

    for (int idx = tid; idx < 512; idx += 256) {
        int m = idx >> 5, k = idx & 31;
        int node = gn0 + m;
        float val = (k < 16 && node < N_NODES) ? x[(size_t)node * 16 + k] : 0.f;
        SL[m * XPITCH + k] = f2bf(val);
    }
    if (tid < 48) {
        int node = gn0 + tid / 3;
        pw[tid] = (node < N_NODES) ? pos[(size_t)node * 3 + tid % 3] : 0.f;
    }
    __syncthreads();

    bf16x8 a[2];
    f32x4 acc;

    a_load<1>(SL, col, quad, a);
    acc = w_tile<1, 32>(a, WT + OFF_NW1T, wv, col, quad, mk4(nb1[wv * 16 + col]));
    __syncthreads();
    w_store1(SL, wv, col, quad, acc, true);
    __syncthreads();

    a_load<2>(SL, col, quad, a);
    acc = w_tile<2, 64>(a, WT + OFF_NW2T, wv, col, quad, mk4(nb2[wv * 16 + col]));
    __syncthreads();
    w_store1(SL, wv, col, quad, acc, false);
    __syncthreads();

    const unsigned short* aT = WT + OFF_LYR;
    const unsigned short* bT = aT + 4096;
    const float* W1c = lW1f + 128 * 64;

    a_load<2>(SL, col, quad, a);
    acc = w_tile<2, 64>(a, aT, wv, col, quad, mk4(0.f));
    g_store1(u, gn0, wv, col, quad, acc);

    int ch = wv * 16 + col;
    acc = w_tile<2, 64>(a, bT, wv, col, quad, mk4(lb1[ch]));
    float w0 = W1c[ch], w1 = W1c[64 + ch], w2 = W1c[128 + ch];
#pragma unroll
    for (int r = 0; r < 4; ++r) {
        int rr = quad * 4 + r;
        acc[r] += pw[rr * 3 + 0] * w0 + pw[rr * 3 + 1] * w1 + pw[rr * 3 + 2] * w2;
    }
    g_store1(v, gn0, wv, col, quad, acc);
}

// ---------------------------------------------------------------------------
// kAgg: wave/node, 16 lanes/edge; quarter q owns edges b+4q..b+4q+3
// (stride 16) -> 4 independent ushort4 row-gathers in flight per quarter,
// 16 per wave. Tail (<16 edges) via stride-4 loop. shfl_xor(16|32) reduce.
// aggH may alias u (u row read before any write; wave owns row n).
// High occupancy (12500 blocks) hides gather latency.
// ---------------------------------------------------------------------------
__global__ __launch_bounds__(256) void kAgg(const int* __restrict__ rowPtr,
                                            const unsigned short* __restrict__ srcList,
                                            const unsigned short* __restrict__ u,
                                            const unsigned short* __restrict__ v,
                                            unsigned short* __restrict__ aggH) {
    int gt = blockIdx.x * 256 + threadIdx.x;
    int n = gt >> 6;
    int lane = gt & 63;
    if (n >= N_NODES) return;
    int sub = lane & 15;
    int q = lane >> 4;

    ushort4 uu = *(const ushort4*)(u + (size_t)n * 64 + sub * 4);
    float u0 = bf2f(uu.x), u1 = bf2f(uu.y), u2 = bf2f(uu.z), u3 = bf2f(uu.w);

    int b = rowPtr[n], e = rowPtr[n + 1];
    int deg = e - b;
    int full16 = deg & ~15;
    float a0 = 0.f, a1 = 0.f, a2 = 0.f, a3 = 0.f;

    for (int g0 = 0; g0 < full16; g0 += 16) {
        int i = b + g0 + 4 * q;
        int s0 = srcList[i];
        int s1 = srcList[i + 1];
        int s2 = srcList[i + 2];
        int s3 = srcList[i + 3];
        ushort4 w0 = *(const ushort4*)(v + (size_t)s0 * 64 + sub * 4);
        ushort4 w1 = *(const ushort4*)(v + (size_t)s1 * 64 + sub * 4);
        ushort4 w2 = *(const ushort4*)(v + (size_t)s2 * 64 + sub * 4);
        ushort4 w3 = *(const ushort4*)(v + (size_t)s3 * 64 + sub * 4);
        a0 += fmaxf(u0 + bf2f(w0.x), 0.f) + fmaxf(u0 + bf2f(w1.x), 0.f)
            + fmaxf(u0 + bf2f(w2.x), 0.f) + fmaxf(u0 + bf2f(w3.x), 0.f);
        a1 += fmaxf(u1 + bf2f(w0.y), 0.f) + fmaxf(u1 + bf2f(w1.y), 0.f)
            + fmaxf(u1 + bf2f(w2.y), 0.f) + fmaxf(u1 + bf2f(w3.y), 0.f);
        a2 += fmaxf(u2 + bf2f(w0.z), 0.f) + fmaxf(u2 + bf2f(w1.z), 0.f)
            + fmaxf(u2 + bf2f(w2.z), 0.f) + fmaxf(u2 + bf2f(w3.z), 0.f);
        a3 += fmaxf(u3 + bf2f(w0.w), 0.f) + fmaxf(u3 + bf2f(w1.w), 0.f)
            + fmaxf(u3 + bf2f(w2.w), 0.f) + fmaxf(u3 + bf2f(w3.w), 0.f);
    }
    for (int i = b + full16 + q; i < e; i += 4) {
        int s0 = srcList[i];
        ushort4 w0 = *(const ushort4*)(v + (size_t)s0 * 64 + sub * 4);
        a0 += fmaxf(u0 + bf2f(w0.x), 0.f);
        a1 += fmaxf(u1 + bf2f(w0.y), 0.f);
        a2 += fmaxf(u2 + bf2f(w0.z), 0.f);
        a3 += fmaxf(u3 + bf2f(w0.w), 0.f);
    }

    a0 += __shfl_xor(a0, 16); a0 += __shfl_xor(a0, 32);
    a1 += __shfl_xor(a1, 16); a1 += __shfl_xor(a1, 32);
    a2 += __shfl_xor(a2, 16); a2 += __shfl_xor(a2, 32);
    a3 += __shfl_xor(a3, 16); a3 += __shfl_xor(a3, 32);

    if (q == 0) {
        ushort4 o;
        o.x = f2bf(a0); o.y = f2bf(a1); o.z = f2bf(a2); o.w = f2bf(a3);
        *(ushort4*)(aggH + (size_t)n * 64 + sub * 4) = o;
    }
}

// ---------------------------------------------------------------------------
// kB (layers 0,1): one 16-node group per block, 4 waves N-split, barriers
// between stages. Reads aggH (=u) rows into LDS, writes new u (own rows,
// after read) and v.
// ---------------------------------------------------------------------------
__global__ __launch_bounds__(256) void kB(
    const float* __restrict__ pos, const int* __restrict__ rowPtr,
    const unsigned short* __restrict__ WT, int l,
    const float* __restrict__ lb2, const float* __restrict__ gb1,
    const float* __restrict__ gb2,
    const float* __restrict__ lW1f_next, const float* __restrict__ b1n,
    unsigned short* __restrict__ u, unsigned short* __restrict__ v) {
    __shared__ unsigned short SL[16 * XPITCH];
    __shared__ float pw[48];
    __shared__ int rp[17];
    int tid = threadIdx.x;
    int lane = tid & 63;
    int wv = __builtin_amdgcn_readfirstlane(tid >> 6);
    int gn0 = blockIdx.x * 16;
    int col = lane & 15, quad = lane >> 4;

    const unsigned short* LYR = WT + OFF_LYR + (size_t)l * LYR_SZ;
    const unsigned short* lW2T = LYR + 2 * 4096;
    const unsigned short* gW1T = LYR + 3 * 4096;
    const unsigned short* gW2T = LYR + 4 * 4096;
    const unsigned short* aTn = WT + OFF_LYR + (size_t)(l + 1) * LYR_SZ;
    const unsigned short* bTn = aTn + 4096;

    // aggH rows (aggH == u) -> SL
    const uint4* ag = (const uint4*)(u + (size_t)gn0 * 64);
    if (tid < 128) {
        int m = tid >> 3, sg = tid & 7;
        uint4 d = (gn0 + m < N_NODES) ? ag[tid] : make_uint4(0u, 0u, 0u, 0u);
        *(uint4*)&SL[m * XPITCH + sg * 8] = d;
    }
    if (tid < 48) {
        int node = gn0 + tid / 3;
        pw[tid] = (node < N_NODES) ? pos[(size_t)node * 3 + tid % 3] : 0.f;
    }
    if (tid < 17) rp[tid] = rowPtr[min(gn0 + tid, N_NODES)];
    __syncthreads();

    bf16x8 a[2];
    f32x4 acc;
    float dgr[4];
#pragma unroll
    for (int r = 0; r < 4; ++r)
        dgr[r] = (float)(rp[quad * 4 + r + 1] - rp[quad * 4 + r]);

    {
        float b = lb2[wv * 16 + col];
        f32x4 init = {dgr[0] * b, dgr[1] * b, dgr[2] * b, dgr[3] * b};
        a_load<2>(SL, col, quad, a);
        acc = w_tile<2, 64>(a, lW2T, wv, col, quad, init);
    }
    __syncthreads();
    w_store1(SL, wv, col, quad, acc, false);
    __syncthreads();

    a_load<2>(SL, col, quad, a);
    acc = w_tile<2, 64>(a, gW1T, wv, col, quad, mk4(gb1[wv * 16 + col]));
    __syncthreads();
    w_store1(SL, wv, col, quad, acc, true);
    __syncthreads();

    a_load<2>(SL, col, quad, a);
    acc = w_tile<2, 64>(a, gW2T, wv, col, quad, mk4(gb2[wv * 16 + col]));
    __syncthreads();
    w_store1(SL, wv, col, quad, acc, true);
    __syncthreads();

    a_load<2>(SL, col, quad, a);
    acc = w_tile<2, 64>(a, aTn, wv, col, quad, mk4(0.f));
    g_store1(u, gn0, wv, col, quad, acc);

    const float* W1c = lW1f_next + 128 * 64;
    int ch = wv * 16 + col;
    acc = w_tile<2, 64>(a, bTn, wv, col, quad, mk4(b1n[ch]));
    float w0 = W1c[ch], w1 = W1c[64 + ch], w2 = W1c[128 + ch];
#pragma unroll
    for (int r = 0; r < 4; ++r) {
        int rr = quad * 4 + r;
        acc[r] += pw[rr * 3 + 0] * w0 + pw[rr * 3 + 1] * w1 + pw[rr * 3 + 2] * w2;
    }
    g_store1(v, gn0, wv, col, quad, acc);
}

// ---------------------------------------------------------------------------
// kC (layer 2): one 16-node group per block, 4 waves N-split + readout bins
// ---------------------------------------------------------------------------
__global__ __launch_bounds__(256) void kC(
    const int* __restrict__ rowPtr, const int* __restrict__ batch,
    const unsigned short* __restrict__ WT,
    const float* __restrict__ lb2, const float* __restrict__ gb1,
    const float* __restrict__ gb2,
    const float* __restrict__ lin1b, const float* __restrict__ lin2b,
    const unsigned short* __restrict__ u, float* __restrict__ out) {
    __shared__ unsigned short SL[16 * XPITCH];
    __shared__ int rp[17];
    __shared__ int batchW[16];
    __shared__ float bins[16 * 8];
    int tid = threadIdx.x;
    int lane = tid & 63;
    int wv = __builtin_amdgcn_readfirstlane(tid >> 6);
    int gn0 = blockIdx.x * 16;   // N_NODES % 16 == 0: all groups full
    int col = lane & 15, quad = lane >> 4;

    const unsigned short* LYR = WT + OFF_LYR + 2 * LYR_SZ;
    const unsigned short* lW2T = LYR + 2 * 4096;
    const unsigned short* gW1T = LYR + 3 * 4096;
    const unsigned short* gW2T = LYR + 4 * 4096;
    const unsigned short* lin1T = WT + OFF_LIN1T;
    const unsigned short* lin2T = WT + OFF_LIN2T;

    const uint4* ag = (const uint4*)(u + (size_t)gn0 * 64);
    if (tid < 128) {
        int m = tid >> 3, sg = tid & 7;
        *(uint4*)&SL[m * XPITCH + sg * 8] = ag[tid];
    }
    if (tid < 17) rp[tid] = rowPtr[gn0 + tid];
    if (tid < 16) batchW[tid] = batch[gn0 + tid];
    if (tid >= 128 && tid < 256) bins[tid - 128] = 0.f;
    __syncthreads();

    bf16x8 a[2];
    f32x4 acc;
    float dgr[4];
#pragma unroll
    for (int r = 0; r < 4; ++r)
        dgr[r] = (float)(rp[quad * 4 + r + 1] - rp[quad * 4 + r]);

    {
        float b = lb2[wv * 16 + col];
        f32x4 init = {dgr[0] * b, dgr[1] * b, dgr[2] * b, dgr[3] * b};
        a_load<2>(SL, col, quad, a);
        acc = w_tile<2, 64>(a, lW2T, wv, col, quad, init);
    }
    __syncthreads();
    w_store1(SL, wv, col, quad, acc, false);
    __syncthreads();

    a_load<2>(SL, col, quad, a);
    acc = w_tile<2, 64>(a, gW1T, wv, col, quad, mk4(gb1[wv * 16 + col]));
    __syncthreads();
    w_store1(SL, wv, col, quad, acc, true);
    __syncthreads();

    a_load<2>(SL, col, quad, a);
    acc = w_tile<2, 64>(a, gW2T, wv, col, quad, mk4(gb2[wv * 16 + col]));
    __syncthreads();
    w_store1(SL, wv, col, quad, acc, true);
    __syncthreads();

    // lin1: 32 output cols -> waves 0,1 only
    a_load<2>(SL, col, quad, a);
    if (wv < 2)
        acc = w_tile<2, 64>(a, lin1T, wv, col, quad, mk4(lin1b[wv * 16 + col]));
    __syncthreads();
    if (wv < 2) w_store1(SL, wv, col, quad, acc, true);
    __syncthreads();

    // lin2: 8 output cols -> wave 0 only; accumulate into per-block bins
    if (wv == 0) {
        a_load<1>(SL, col, quad, a);
        f32x4 o = w_tile<1, 32>(a, lin2T, 0, col, quad,
                                mk4(col < 8 ? lin2b[col] : 0.f));
        int gmin = batchW[0];
        if (col < 8) {
#pragma unroll
            for (int r = 0; r < 4; ++r) {
                int nl = quad * 4 + r;
                atomicAdd(&bins[(batchW[nl] - gmin) * 8 + col], o[r]);
            }
        }
    }
    __syncthreads();
    int gmin = batchW[0];
    int nb8 = (batchW[15] - gmin + 1) * 8;
    for (int idx = tid; idx < nb8; idx += 256)
        atomAddF(&out[gmin * 8 + idx], bins[idx]);
}

// ---------------------------------------------------------------------------
// launch
// ---------------------------------------------------------------------------
extern "C" void kernel_launch(void* const* d_in, const int* in_sizes, int n_in,
                              void* d_out, int out_size, void* d_ws, size_t ws_size,
                              hipStream_t stream) {
    const float* x     = (const float*)d_in[0];
    const float* pos   = (const float*)d_in[1];
    const int*   ei    = (const int*)d_in[2];
    const int*   batch = (const int*)d_in[3];
    const float* nW1   = (const float*)d_in[4];
    const float* nb1   = (const float*)d_in[5];
    const float* nW2   = (const float*)d_in[6];
    const float* nb2   = (const float*)d_in[7];
    const float* lW1   = (const float*)d_in[8];
    const float* lb1   = (const float*)d_in[9];
    const float* lW2   = (const float*)d_in[10];
    const float* lb2   = (const float*)d_in[11];
    const float* gW1   = (const float*)d_in[12];
    const float* gb1   = (const float*)d_in[13];
    const float* gW2   = (const float*)d_in[14];
    const float* gb2   = (const float*)d_in[15];
    const float* lin1W = (const float*)d_in[16];
    const float* lin1b = (const float*)d_in[17];
    const float* lin2W = (const float*)d_in[18];
    const float* lin2b = (const float*)d_in[19];
    float* out = (float*)d_out;

    // workspace (u doubles as aggH)
    unsigned short* u  = (unsigned short*)d_ws;          // N*64 bf16
    unsigned short* v  = u + (size_t)N_NODES * 64;       // N*64 bf16
    unsigned short* WT = v + (size_t)N_NODES * 64;       // WT_TOTAL bf16
    int* gHist = (int*)(WT + WT_TOTAL);                  // NB
    int* bucketOff = gHist + NB;                         // NB+1
    int* cursor = bucketOff + NB + 1;                    // NB
    int* rowPtr = cursor + NB;                           // N+1
    int* packs = rowPtr + N_NODES + 1;                   // E int
    unsigned short* srcList = (unsigned short*)(packs + N_EDGES); // E ushort
    unsigned short* aggH = u;

    const int aggBlocks = (N_NODES * 64 + 255) / 256;

    kPrep<<<(WT_TOTAL + 255) / 256, 256, 0, stream>>>(nW1, nW2, lW1, lW2, gW1, gW2,
                                                      lin1W, lin2W, WT, gHist, out);
    kHist<<<(N_EDGES + HEPB - 1) / HEPB, 256, 0, stream>>>(ei, gHist);
    kScanB<<<1, 256, 0, stream>>>(gHist, bucketOff, cursor);
    kScat<<<(N_EDGES + SEPB - 1) / SEPB, 256, 0, stream>>>(ei, cursor, packs);
    kSortA<<<NB + NGRP, 256, 0, stream>>>(bucketOff, packs, srcList, rowPtr,
                                          x, pos, WT, nb1, nb2, lW1, lb1, u, v);

    for (int l = 0; l < 3; ++l) {
        kAgg<<<aggBlocks, 256, 0, stream>>>(rowPtr, srcList, u, v, aggH);
        if (l < 2) {
            kB<<<NGRP, 256, 0, stream>>>(
                pos, rowPtr, WT, l,
                lb2 + l * 64, gb1 + l * 64, gb2 + l * 64,
                lW1 + (size_t)(l + 1) * 131 * 64, lb1 + (l + 1) * 64,
                u, v);
        } else {
            kC<<<NGRP, 256, 0, stream>>>(
                rowPtr, batch, WT,
                lb2 + l * 64, gb1 + l * 64, gb2 + l * 64,
                lin1b, lin2b, u, out);
        }
    }
}